// Round 9
// baseline (51.104 us; speedup 1.0000x reference)
//
#include <hip/hip_runtime.h>

// 2x upsample, binomial blur [1,4,6,4,1]/8 per axis, edge clamp.
// r8 flat-store structure (thread = one w-quad of one h row, both output
// d-planes; every wave store = one contiguous 1KB span), A/B change:
// PLAIN stores instead of nontemporal. This is the fill-kernel cell of the
// {pattern}x{policy} matrix: contiguous + L2 write-back (fills hit 7 TB/s).
// Unified weights: per axis even taps (1,6,1), odd taps (0,4,4), one final
// exact *1/512 per output.

typedef float f32x4 __attribute__((ext_vector_type(4)));

constexpr int DIN = 48, HIN = 48, WIN = 48;
constexpr int HW = HIN * WIN;     // 2304 input plane
constexpr int PS = 96 * 96;       // 9216 output plane (floats)

__global__ __launch_bounds__(256) void Upsample2x2x2_kernel(
    const float* __restrict__ x, float* __restrict__ out)
{
    const int p  = blockIdx.x * 256 + threadIdx.x;  // quad index in plane, 0..2303
    const int a  = blockIdx.y;                      // input d; output planes 2a, 2a+1
    const int nc = blockIdx.z;

    const int h    = p / 24;          // output h row 0..95 (const-div -> mulhi)
    const int s    = p - h * 24;      // w-quad 0..23, input w0 = 2s
    const int b    = h >> 1;
    const int hodd = h & 1;

    const float* __restrict__ xb = x + nc * (DIN * HW);

    // d neighbor rows; even plane weights (1,6,1), odd plane (0,4,4)
    const int ii[3] = { a > 0 ? a - 1 : 0, a, a + 1 < DIN ? a + 1 : DIN - 1 };

    // h neighbor rows + weights: even h: (c(b-1),b,c(b+1)) w(1,6,1);
    // odd h: (b, c(b+1), c(b+1)) w(4,4,0)
    const int jb1 = b + 1 < HIN ? b + 1 : HIN - 1;
    const int jj[3] = { hodd ? b : (b > 0 ? b - 1 : 0),
                        hodd ? jb1 : b,
                        jb1 };
    const float hw[3] = { hodd ? 4.f : 1.f, hodd ? 4.f : 6.f, hodd ? 0.f : 1.f };

    // single 16B load per row covering u0..u3 = x[c(w0-1)..c(w0+2)] (r7 trick)
    const bool lo = (s == 0), hi = (s == 23);
    const int base = 2 * s + (lo ? 0 : (hi ? -2 : -1));

    // h-combine raw u-vectors (4 wide) per d-row
    float hc[3][4];
    #pragma unroll
    for (int i = 0; i < 3; i++) {
        const float* __restrict__ xd = xb + ii[i] * HW;
        float a0 = 0.f, a1 = 0.f, a2 = 0.f, a3 = 0.f;
        #pragma unroll
        for (int j = 0; j < 3; j++) {
            const float* __restrict__ row = xd + jj[j] * WIN;
            f32x4 v;
            __builtin_memcpy(&v, row + base, 16);
            float u0 = hi ? v.y : v.x;
            float u1 = lo ? v.x : (hi ? v.z : v.y);
            float u2 = lo ? v.y : (hi ? v.w : v.z);
            float u3 = lo ? v.z : v.w;
            float w = hw[j];
            a0 = fmaf(w, u0, a0);
            a1 = fmaf(w, u1, a1);
            a2 = fmaf(w, u2, a2);
            a3 = fmaf(w, u3, a3);
        }
        hc[i][0] = a0; hc[i][1] = a1; hc[i][2] = a2; hc[i][3] = a3;
    }

    // W-stage per d-row: quad [E(2s), O(2s), E(2s+1), O(2s+1)]
    float Wv[3][4];
    #pragma unroll
    for (int i = 0; i < 3; i++) {
        Wv[i][0] = fmaf(6.f, hc[i][1], hc[i][0]) + hc[i][2];
        Wv[i][1] = (hc[i][1] + hc[i][2]) * 4.f;
        Wv[i][2] = fmaf(6.f, hc[i][2], hc[i][1]) + hc[i][3];
        Wv[i][3] = (hc[i][2] + hc[i][3]) * 4.f;
    }

    // d-combine + one exact *1/512; even plane (1,6,1), odd plane (0,4,4)
    f32x4 e, o;
    e.x = (fmaf(6.f, Wv[1][0], Wv[0][0]) + Wv[2][0]) * (1.f/512);
    e.y = (fmaf(6.f, Wv[1][1], Wv[0][1]) + Wv[2][1]) * (1.f/512);
    e.z = (fmaf(6.f, Wv[1][2], Wv[0][2]) + Wv[2][2]) * (1.f/512);
    e.w = (fmaf(6.f, Wv[1][3], Wv[0][3]) + Wv[2][3]) * (1.f/512);
    o.x = (Wv[1][0] + Wv[2][0]) * (4.f/512);
    o.y = (Wv[1][1] + Wv[2][1]) * (4.f/512);
    o.z = (Wv[1][2] + Wv[2][2]) * (4.f/512);
    o.w = (Wv[1][3] + Wv[2][3]) * (4.f/512);

    float* __restrict__ ob = out + (nc * 96 + 2 * a) * PS;
    *reinterpret_cast<f32x4*>(ob + p * 4)      = e;
    *reinterpret_cast<f32x4*>(ob + PS + p * 4) = o;
}

extern "C" void kernel_launch(void* const* d_in, const int* in_sizes, int n_in,
                              void* d_out, int out_size, void* d_ws, size_t ws_size,
                              hipStream_t stream) {
    const float* x = (const float*)d_in[0];
    float* out = (float*)d_out;
    dim3 grid(9, 48, 64);   // 9*256 = 2304 quads/plane-pair, 48 d-pairs, 64 nc
    Upsample2x2x2_kernel<<<grid, 256, 0, stream>>>(x, out);
}

// Round 10
// 48.245 us; speedup vs baseline: 1.0593x; 1.0593x over previous
//
#include <hip/hip_runtime.h>

// 2x upsample with binomial blur [1,4,6,4,1]/8 per axis, edge clamp.
// Per-axis closed form (clamp c() to [0,47]):
//   y[2a]   = (x[c(a-1)] + 6*x[a] + x[c(a+1)]) / 8
//   y[2a+1] = (x[a] + x[c(a+1)]) / 2
// Each thread: 2x2x2-input block -> 4x4x4 output block (64 floats).
// FINAL: round-3 structure + nontemporal stores — the measured best across
// the full {store pattern}x{cache policy}x{tile}x{occupancy} search:
//   r3+nt 47.8us | r3+plain 50.2 | flat+nt 50.9 | flat+plain 51.1
//   bigger tile (r5) spills: 116us | launch_bounds(,4) (r4): neutral
//   single-16B-load (r7): neutral.  255MB @ ~5.3TB/s effective = op floor.
// All /8,/2 scaling deferred to one exact power-of-two multiply per output.

typedef float f32x4 __attribute__((ext_vector_type(4)));

constexpr int DIN = 48, HIN = 48, WIN = 48;
constexpr int HW = HIN * WIN;          // 2304
constexpr int HOUT = 96, WOUT = 96;
constexpr int PS = HOUT * WOUT;        // output d-plane stride, 9216
constexpr int NC = 64;
constexpr int THREADS = NC * 24 * 24 * 24;  // 884736

__global__ __launch_bounds__(256) void Upsample2x2x2_kernel(
    const float* __restrict__ x, float* __restrict__ out)
{
    int idx = blockIdx.x * 256 + threadIdx.x;
    int t   = idx % 24;        // input w0 = 2t, outputs w 4t..4t+3
    int tmp = idx / 24;
    int b0h = tmp % 24;
    tmp    /= 24;
    int a0h = tmp % 24;
    int nc  = tmp / 24;

    const int a0 = a0h * 2, b0 = b0h * 2, w0 = t * 2;
    const float* __restrict__ xb = x + nc * (DIN * HW);

    const int ai[4] = { a0 > 0 ? a0 - 1 : 0, a0, a0 + 1,
                        a0 + 2 < DIN ? a0 + 2 : DIN - 1 };
    const int bi[4] = { b0 > 0 ? b0 - 1 : 0, b0, b0 + 1,
                        b0 + 2 < HIN ? b0 + 2 : HIN - 1 };
    const int wm = w0 > 0 ? w0 - 1 : 0;
    const int wp = w0 + 2 < WIN ? w0 + 2 : WIN - 1;

    // W-stage (unscaled): per neighbor row, 4 values
    // k0 = E(w0) = u0+6u1+u2 ; k1 = O(w0) = u1+u2
    // k2 = E(w0+1) = u1+6u2+u3 ; k3 = O(w0+1) = u2+u3
    float r[4][4][4];
    #pragma unroll
    for (int i = 0; i < 4; i++) {
        const float* __restrict__ xd = xb + ai[i] * HW;
        #pragma unroll
        for (int j = 0; j < 4; j++) {
            const float* __restrict__ row = xd + bi[j] * WIN;
            float2 m = *reinterpret_cast<const float2*>(row + w0);  // 8B aligned
            float u0 = row[wm];
            float u3 = row[wp];
            float u1 = m.x, u2 = m.y;
            r[i][j][0] = fmaf(6.f, u1, u0) + u2;
            r[i][j][1] = u1 + u2;
            r[i][j][2] = fmaf(6.f, u2, u1) + u3;
            r[i][j][3] = u2 + u3;
        }
    }

    float* __restrict__ ob = out + nc * (2 * DIN * PS);
    const int obase = (a0 * 2 * HOUT + b0 * 2) * WOUT + t * 4;

    #pragma unroll
    for (int win = 0; win < 2; win++) {   // h output pair 2(b0+win), +1
        float He[4][4], Ho[4][4];         // H-combined, per d-row, unscaled
        #pragma unroll
        for (int i = 0; i < 4; i++)
            #pragma unroll
            for (int k = 0; k < 4; k++) {
                He[i][k] = fmaf(6.f, r[i][win + 1][k], r[i][win][k]) + r[i][win + 2][k];
                Ho[i][k] = r[i][win + 1][k] + r[i][win + 2][k];
            }

        #pragma unroll
        for (int ap = 0; ap < 2; ap++) {  // d output pair 2(a0+ap), +1
            float vee[4], voe[4], veo[4], voo[4];
            #pragma unroll
            for (int k = 0; k < 4; k++) {
                vee[k] = fmaf(6.f, He[ap + 1][k], He[ap][k]) + He[ap + 2][k];
                voe[k] = He[ap + 1][k] + He[ap + 2][k];
                veo[k] = fmaf(6.f, Ho[ap + 1][k], Ho[ap][k]) + Ho[ap + 2][k];
                voo[k] = Ho[ap + 1][k] + Ho[ap + 2][k];
            }
            const int rbase = obase + ap * 2 * PS + win * 2 * WOUT;
            // scales: per-axis even=1/8, odd=1/2; w-parity alternates in lane
            f32x4 s0 = { vee[0] * (1.f/512), vee[1] * (1.f/128),
                         vee[2] * (1.f/512), vee[3] * (1.f/128) };
            f32x4 s1 = { veo[0] * (1.f/128), veo[1] * (1.f/32),
                         veo[2] * (1.f/128), veo[3] * (1.f/32) };
            f32x4 s2 = { voe[0] * (1.f/128), voe[1] * (1.f/32),
                         voe[2] * (1.f/128), voe[3] * (1.f/32) };
            f32x4 s3 = { voo[0] * (1.f/32),  voo[1] * (1.f/8),
                         voo[2] * (1.f/32),  voo[3] * (1.f/8) };
            __builtin_nontemporal_store(s0, reinterpret_cast<f32x4*>(ob + rbase));
            __builtin_nontemporal_store(s1, reinterpret_cast<f32x4*>(ob + rbase + WOUT));
            __builtin_nontemporal_store(s2, reinterpret_cast<f32x4*>(ob + rbase + PS));
            __builtin_nontemporal_store(s3, reinterpret_cast<f32x4*>(ob + rbase + PS + WOUT));
        }
    }
}

extern "C" void kernel_launch(void* const* d_in, const int* in_sizes, int n_in,
                              void* d_out, int out_size, void* d_ws, size_t ws_size,
                              hipStream_t stream) {
    const float* x = (const float*)d_in[0];
    float* out = (float*)d_out;
    int blocks = THREADS / 256;  // 3456, exact
    Upsample2x2x2_kernel<<<blocks, 256, 0, stream>>>(x, out);
}